// Round 4
// baseline (615.070 us; speedup 1.0000x reference)
//
#include <hip/hip_runtime.h>
#include <stdint.h>

#define IN_F   4096
#define OUT_F  4096
#define BATCH  4096

#define BM 128
#define BN 128
#define BK 32
#define KSTEPS (IN_F / BK)   // 128

typedef __bf16 bf16x8 __attribute__((ext_vector_type(8)));
typedef float  f32x4  __attribute__((ext_vector_type(4)));
typedef unsigned short u16x8 __attribute__((ext_vector_type(8)));

// ---------- fp32 -> bf16 (RNE) ----------
__device__ inline unsigned short f32_to_bf16_rne(float f) {
    unsigned int u = __float_as_uint(f);
    u += 0x7FFFu + ((u >> 16) & 1u);
    return (unsigned short)(u >> 16);
}

__global__ void cvt2_f32_bf16(const float4* __restrict__ xa,
                              const float4* __restrict__ wa,
                              u16x8* __restrict__ xo,
                              u16x8* __restrict__ wo, int n8_per) {
    int i = blockIdx.x * blockDim.x + threadIdx.x;
    const float4* src;
    u16x8* dst;
    if (i < n8_per) { src = xa; dst = xo; }
    else            { src = wa; dst = wo; i -= n8_per; }
    float4 v0 = src[2 * i];
    float4 v1 = src[2 * i + 1];
    u16x8 o;
    o[0] = f32_to_bf16_rne(v0.x); o[1] = f32_to_bf16_rne(v0.y);
    o[2] = f32_to_bf16_rne(v0.z); o[3] = f32_to_bf16_rne(v0.w);
    o[4] = f32_to_bf16_rne(v1.x); o[5] = f32_to_bf16_rne(v1.y);
    o[6] = f32_to_bf16_rne(v1.z); o[7] = f32_to_bf16_rne(v1.w);
    dst[i] = o;
}

// ---------- flat (no-LDS) bf16 GEMM: C = A * Bt^T + bias ----------
// MFMA A/B fragments are loaded DIRECTLY from global: for fragment group i,
// the wave's 64 lanes (row = lane&15, kchunk = lane>>4) cover 16 rows x 64
// contiguous bytes -> clean 64B segments, L1/L2-served. No LDS => no
// __syncthreads => no vmcnt(0) drain in the K-loop; compiler emits precise
// per-load vmcnt. 2-deep register ping-pong: loads for k+1 issue before the
// MFMA block for k. Intra-block 2x read duplication (waves sharing rows) is
// absorbed by L1 (16KB/K-step working set vs 32KB L1).
__global__ __launch_bounds__(256, 3)
void gemm_flat_bf16(const unsigned short* __restrict__ A,
                    const unsigned short* __restrict__ Bt,
                    const float* __restrict__ bias,
                    float* __restrict__ out) {
    const int tid  = threadIdx.x;
    const int lane = tid & 63;
    const int wv   = tid >> 6;          // wave 0..3
    const int wm   = (wv & 1) * 64;
    const int wn   = (wv >> 1) * 64;

    const int m0 = blockIdx.y * BM;
    const int n0 = blockIdx.x * BN;

    const int fr = lane & 15;           // fragment row within 16-group
    const int kq = (lane >> 4) * 8;     // k sub-chunk (elems)

    const unsigned short* Ab = A  + (size_t)(m0 + wm + fr) * IN_F + kq;
    const unsigned short* Bb = Bt + (size_t)(n0 + wn + fr) * IN_F + kq;

    f32x4 acc[4][4] = {};
    bf16x8 a0[4], b0[4], a1[4], b1[4];

    #pragma unroll
    for (int i = 0; i < 4; ++i) {
        a0[i] = *(const bf16x8*)(Ab + (size_t)i * 16 * IN_F);
        b0[i] = *(const bf16x8*)(Bb + (size_t)i * 16 * IN_F);
    }

    for (int kt = 0; kt < KSTEPS; kt += 2) {
        // prefetch k+1 into set1
        const unsigned short* A1 = Ab + (size_t)(kt + 1) * BK;
        const unsigned short* B1 = Bb + (size_t)(kt + 1) * BK;
        #pragma unroll
        for (int i = 0; i < 4; ++i) {
            a1[i] = *(const bf16x8*)(A1 + (size_t)i * 16 * IN_F);
            b1[i] = *(const bf16x8*)(B1 + (size_t)i * 16 * IN_F);
        }
        // MFMA on set0 (k = kt)
        #pragma unroll
        for (int i = 0; i < 4; ++i)
            #pragma unroll
            for (int j = 0; j < 4; ++j)
                acc[i][j] = __builtin_amdgcn_mfma_f32_16x16x32_bf16(
                    a0[i], b0[j], acc[i][j], 0, 0, 0);

        // prefetch k+2 into set0 (wrap to 0 on last iter; values unused)
        const int k2 = (kt + 2 < KSTEPS) ? (kt + 2) : 0;
        const unsigned short* A2 = Ab + (size_t)k2 * BK;
        const unsigned short* B2 = Bb + (size_t)k2 * BK;
        #pragma unroll
        for (int i = 0; i < 4; ++i) {
            a0[i] = *(const bf16x8*)(A2 + (size_t)i * 16 * IN_F);
            b0[i] = *(const bf16x8*)(B2 + (size_t)i * 16 * IN_F);
        }
        // MFMA on set1 (k = kt+1)
        #pragma unroll
        for (int i = 0; i < 4; ++i)
            #pragma unroll
            for (int j = 0; j < 4; ++j)
                acc[i][j] = __builtin_amdgcn_mfma_f32_16x16x32_bf16(
                    a1[i], b1[j], acc[i][j], 0, 0, 0);
    }

    // Epilogue. C/D layout (m89/m91): col = lane&15, row = (lane>>4)*4 + reg
    const int ocol = n0 + wn;
    float bj[4];
    #pragma unroll
    for (int j = 0; j < 4; ++j) bj[j] = bias[ocol + j * 16 + fr];

    const int rsel = (lane >> 4) * 4;
    #pragma unroll
    for (int i = 0; i < 4; ++i) {
        #pragma unroll
        for (int v = 0; v < 4; ++v) {
            const int row = m0 + wm + i * 16 + rsel + v;
            float* orow = out + (size_t)row * OUT_F + ocol + fr;
            #pragma unroll
            for (int j = 0; j < 4; ++j)
                orow[j * 16] = acc[i][j][v] + bj[j];
        }
    }
}

// ---------- fallback: correct fp32 tiled GEMM (only if ws too small) ----------
__global__ void fb_gemm(const float* __restrict__ A, const float* __restrict__ W,
                        const float* __restrict__ bias, float* __restrict__ out) {
    __shared__ float tA[16][17];
    __shared__ float tW[16][17];
    const int tx = threadIdx.x, ty = threadIdx.y;
    const int row = blockIdx.y * 16 + ty;
    const int col = blockIdx.x * 16 + tx;
    float s = 0.f;
    for (int k = 0; k < IN_F; k += 16) {
        tA[ty][tx] = A[(size_t)row * IN_F + k + tx];
        tW[ty][tx] = W[(size_t)(blockIdx.x * 16 + ty) * IN_F + k + tx];
        __syncthreads();
        #pragma unroll
        for (int kk = 0; kk < 16; ++kk) s += tA[ty][kk] * tW[tx][kk];
        __syncthreads();
    }
    out[(size_t)row * OUT_F + col] = s + bias[col];
}

extern "C" void kernel_launch(void* const* d_in, const int* in_sizes, int n_in,
                              void* d_out, int out_size, void* d_ws, size_t ws_size,
                              hipStream_t stream) {
    const float* x = (const float*)d_in[0];
    const float* W = (const float*)d_in[1];
    const float* b = (const float*)d_in[2];
    float* out = (float*)d_out;

    const size_t elems      = (size_t)BATCH * IN_F;
    const size_t bf16_bytes = elems * 2;

    if (ws_size >= 2 * bf16_bytes) {
        unsigned short* xb = (unsigned short*)d_ws;
        unsigned short* wb = (unsigned short*)((char*)d_ws + bf16_bytes);

        const int n8_per  = (int)(elems / 8);
        const int threads = 2 * n8_per;
        cvt2_f32_bf16<<<(threads + 255) / 256, 256, 0, stream>>>(
            (const float4*)x, (const float4*)W, (u16x8*)xb, (u16x8*)wb, n8_per);

        dim3 grid(OUT_F / BN, BATCH / BM);  // 32 x 32
        gemm_flat_bf16<<<grid, 256, 0, stream>>>(xb, wb, b, out);
    } else {
        dim3 grid(OUT_F / 16, BATCH / 16);
        fb_gemm<<<grid, dim3(16, 16), 0, stream>>>(x, W, b, out);
    }
}

// Round 5
// 331.522 us; speedup vs baseline: 1.8553x; 1.8553x over previous
//
#include <hip/hip_runtime.h>
#include <stdint.h>

#define IN_F   4096
#define OUT_F  4096
#define BATCH  4096

#define BM 128
#define BN 128
#define BK 32
#define KSTEPS (IN_F / BK)   // 128

typedef __bf16 bf16x8 __attribute__((ext_vector_type(8)));
typedef float  f32x4  __attribute__((ext_vector_type(4)));
typedef unsigned short u16x8 __attribute__((ext_vector_type(8)));

// ---------- fp32 -> bf16 (RNE) ----------
__device__ inline unsigned short f32_to_bf16_rne(float f) {
    unsigned int u = __float_as_uint(f);
    u += 0x7FFFu + ((u >> 16) & 1u);
    return (unsigned short)(u >> 16);
}

__global__ void cvt2_f32_bf16(const float4* __restrict__ xa,
                              const float4* __restrict__ wa,
                              u16x8* __restrict__ xo,
                              u16x8* __restrict__ wo, int n8_per) {
    int i = blockIdx.x * blockDim.x + threadIdx.x;
    const float4* src;
    u16x8* dst;
    if (i < n8_per) { src = xa; dst = xo; }
    else            { src = wa; dst = wo; i -= n8_per; }
    float4 v0 = src[2 * i];
    float4 v1 = src[2 * i + 1];
    u16x8 o;
    o[0] = f32_to_bf16_rne(v0.x); o[1] = f32_to_bf16_rne(v0.y);
    o[2] = f32_to_bf16_rne(v0.z); o[3] = f32_to_bf16_rne(v0.w);
    o[4] = f32_to_bf16_rne(v1.x); o[5] = f32_to_bf16_rne(v1.y);
    o[6] = f32_to_bf16_rne(v1.z); o[7] = f32_to_bf16_rne(v1.w);
    dst[i] = o;
}

// ---------- VGPR-staged double-buffered bf16 GEMM: C = A * Bt^T + bias ----------
// AITER-style pipeline: global->VGPR prefetch of tile k+1 issues BEFORE the
// MFMA block for tile k; the vmcnt wait sits at the ds_write (after ~300 cyc
// of MFMA), so loads are already complete and the pre-barrier vmcnt(0) drain
// is free. One __syncthreads per K-step (vs m97's DMA structure where every
// barrier hard-drains the global_load_lds queue).
__global__ void gemm_dbuf_bf16(const unsigned short* __restrict__ A,
                               const unsigned short* __restrict__ Bt,
                               const float* __restrict__ bias,
                               float* __restrict__ out) {
    __shared__ __align__(16) unsigned short lsA[2][BM * BK];  // 2 x 8 KB
    __shared__ __align__(16) unsigned short lsB[2][BN * BK];  // 2 x 8 KB

    const int tid  = threadIdx.x;
    const int lane = tid & 63;
    const int wv   = tid >> 6;          // wave 0..3
    const int wm   = (wv & 1) * 64;
    const int wn   = (wv >> 1) * 64;

    const int m0 = blockIdx.y * BM;
    const int n0 = blockIdx.x * BN;

    // Staging: wave wv owns rows [wv*32, wv*32+32) of the A- and B-tiles.
    // lane l: row srow = l>>2 (and +16), 8-elem chunk l&3. 16B/lane, coalesced.
    const int srow = lane >> 2;
    const int scol = (lane & 3) * 8;

    const unsigned short* gA0 = A  + (size_t)(m0 + wv * 32 + srow) * IN_F + scol;
    const unsigned short* gA1 = gA0 + 16 * (size_t)IN_F;
    const unsigned short* gB0 = Bt + (size_t)(n0 + wv * 32 + srow) * IN_F + scol;
    const unsigned short* gB1 = gB0 + 16 * (size_t)IN_F;

    const int woff0 = (wv * 32 + srow) * BK + scol;
    const int woff1 = woff0 + 16 * BK;

    // MFMA A/B-operand layout: row = lane&15, k = (lane>>4)*8 + j
    const int fr = lane & 15;
    const int kq = (lane >> 4) * 8;

    // ---- prologue: stage tile 0 ----
    u16x8 rA0 = *(const u16x8*)gA0, rA1 = *(const u16x8*)gA1;
    u16x8 rB0 = *(const u16x8*)gB0, rB1 = *(const u16x8*)gB1;
    gA0 += BK; gA1 += BK; gB0 += BK; gB1 += BK;
    *(u16x8*)&lsA[0][woff0] = rA0;
    *(u16x8*)&lsA[0][woff1] = rA1;
    *(u16x8*)&lsB[0][woff0] = rB0;
    *(u16x8*)&lsB[0][woff1] = rB1;
    __syncthreads();

    f32x4 acc[4][4] = {};
    int cur = 0;

    for (int kt = 1; kt < KSTEPS; ++kt) {
        // prefetch tile kt into registers (vmcnt consumed only at ds_write below)
        rA0 = *(const u16x8*)gA0; rA1 = *(const u16x8*)gA1;
        rB0 = *(const u16x8*)gB0; rB1 = *(const u16x8*)gB1;
        gA0 += BK; gA1 += BK; gB0 += BK; gB1 += BK;

        // compute on tile kt-1 from buffer `cur`
        bf16x8 aF[4], bF[4];
        #pragma unroll
        for (int i = 0; i < 4; ++i)
            aF[i] = *(const bf16x8*)&lsA[cur][(wm + i * 16 + fr) * BK + kq];
        #pragma unroll
        for (int j = 0; j < 4; ++j)
            bF[j] = *(const bf16x8*)&lsB[cur][(wn + j * 16 + fr) * BK + kq];

        #pragma unroll
        for (int i = 0; i < 4; ++i)
            #pragma unroll
            for (int j = 0; j < 4; ++j)
                acc[i][j] = __builtin_amdgcn_mfma_f32_16x16x32_bf16(
                    aF[i], bF[j], acc[i][j], 0, 0, 0);

        // write staged tile kt to the other buffer; loads are ~done by now
        const int nxt = cur ^ 1;
        *(u16x8*)&lsA[nxt][woff0] = rA0;
        *(u16x8*)&lsA[nxt][woff1] = rA1;
        *(u16x8*)&lsB[nxt][woff0] = rB0;
        *(u16x8*)&lsB[nxt][woff1] = rB1;
        __syncthreads();
        cur = nxt;
    }

    // ---- final K-step ----
    {
        bf16x8 aF[4], bF[4];
        #pragma unroll
        for (int i = 0; i < 4; ++i)
            aF[i] = *(const bf16x8*)&lsA[cur][(wm + i * 16 + fr) * BK + kq];
        #pragma unroll
        for (int j = 0; j < 4; ++j)
            bF[j] = *(const bf16x8*)&lsB[cur][(wn + j * 16 + fr) * BK + kq];
        #pragma unroll
        for (int i = 0; i < 4; ++i)
            #pragma unroll
            for (int j = 0; j < 4; ++j)
                acc[i][j] = __builtin_amdgcn_mfma_f32_16x16x32_bf16(
                    aF[i], bF[j], acc[i][j], 0, 0, 0);
    }

    // Epilogue. C/D layout (m89/m91): col = lane&15, row = (lane>>4)*4 + reg
    const int ocol = n0 + wn;
    float bj[4];
    #pragma unroll
    for (int j = 0; j < 4; ++j) bj[j] = bias[ocol + j * 16 + fr];

    const int rsel = (lane >> 4) * 4;
    #pragma unroll
    for (int i = 0; i < 4; ++i) {
        #pragma unroll
        for (int v = 0; v < 4; ++v) {
            const int row = m0 + wm + i * 16 + rsel + v;
            float* orow = out + (size_t)row * OUT_F + ocol + fr;
            #pragma unroll
            for (int j = 0; j < 4; ++j)
                orow[j * 16] = acc[i][j][v] + bj[j];
        }
    }
}

// ---------- fallback: correct fp32 tiled GEMM (only if ws too small) ----------
__global__ void fb_gemm(const float* __restrict__ A, const float* __restrict__ W,
                        const float* __restrict__ bias, float* __restrict__ out) {
    __shared__ float tA[16][17];
    __shared__ float tW[16][17];
    const int tx = threadIdx.x, ty = threadIdx.y;
    const int row = blockIdx.y * 16 + ty;
    const int col = blockIdx.x * 16 + tx;
    float s = 0.f;
    for (int k = 0; k < IN_F; k += 16) {
        tA[ty][tx] = A[(size_t)row * IN_F + k + tx];
        tW[ty][tx] = W[(size_t)(blockIdx.x * 16 + ty) * IN_F + k + tx];
        __syncthreads();
        #pragma unroll
        for (int kk = 0; kk < 16; ++kk) s += tA[ty][kk] * tW[tx][kk];
        __syncthreads();
    }
    out[(size_t)row * OUT_F + col] = s + bias[col];
}

extern "C" void kernel_launch(void* const* d_in, const int* in_sizes, int n_in,
                              void* d_out, int out_size, void* d_ws, size_t ws_size,
                              hipStream_t stream) {
    const float* x = (const float*)d_in[0];
    const float* W = (const float*)d_in[1];
    const float* b = (const float*)d_in[2];
    float* out = (float*)d_out;

    const size_t elems      = (size_t)BATCH * IN_F;
    const size_t bf16_bytes = elems * 2;

    if (ws_size >= 2 * bf16_bytes) {
        unsigned short* xb = (unsigned short*)d_ws;
        unsigned short* wb = (unsigned short*)((char*)d_ws + bf16_bytes);

        const int n8_per  = (int)(elems / 8);
        const int threads = 2 * n8_per;
        cvt2_f32_bf16<<<(threads + 255) / 256, 256, 0, stream>>>(
            (const float4*)x, (const float4*)W, (u16x8*)xb, (u16x8*)wb, n8_per);

        dim3 grid(OUT_F / BN, BATCH / BM);  // 32 x 32
        gemm_dbuf_bf16<<<grid, 256, 0, stream>>>(xb, wb, b, out);
    } else {
        dim3 grid(OUT_F / 16, BATCH / 16);
        fb_gemm<<<grid, dim3(16, 16), 0, stream>>>(x, W, b, out);
    }
}